// Round 11
// baseline (131.321 us; speedup 1.0000x reference)
//
#include <hip/hip_runtime.h>

// RandomForest: 131072 samples x 64 feat, 64 trees depth 12, 8-class vote.
//
// R11 = R10 with the nontemporal-load compile fix (ext_vector_type alias
// instead of HIP uint4 class). Theory unchanged: R9 is L2-random-line-bound
// (~27 TB/s ~= 78% of L2 ceiling); per-CU tree diversity means NOTHING is
// L1-resident. Fix: (a) 1 block/CU, 8 barrier-aligned 8-tree windows, both
// thread-halves split the SAME window (ILP=4 each) -> CU walks 8 trees at a
// time; (b) sub16 gather is nontemporal (no L1 alloc) so pair4 (32 KiB =
// exactly L1) + shallow (11 KiB) become L1-resident.
// Revert signal: FETCH_SIZE >100 MB means nt bypassed L2 -> undo nt.

constexpr int kSamples  = 131072;
constexpr int kFeat     = 64;
constexpr int kTrees    = 64;
constexpr int kInternal = 4095;
constexpr int kClasses  = 8;

constexpr int TPB  = 1024;
constexpr int SPB  = 512;                        // samples per block
constexpr int XSTR = 512;                        // dwords; f column = f<<11 bytes
constexpr int XLDS_BYTES = kFeat * XSTR * 4;     // 131072 B
constexpr int ILP  = 4;                          // chains per thread (half-window)
constexpr int WINDOW = 8;                        // trees per aligned window

typedef unsigned int u32x4 __attribute__((ext_vector_type(4)));  // nt-load-able

// Pair p covers levels 2p,2p+1; entries-before offsets {0,1,5,21,85}, 341/tree,
// stride 512 -> tree base = t<<9.
struct Pair  { float thr0, thrL, thrR; unsigned meta; };  // meta: f0|fL<<6|fR<<12
struct Sub16 { float thr10, thrL, thrR; unsigned meta; }; // +lv0..lv3 <<18,21,24,27

__global__ __launch_bounds__(256) void pack_pairs_kernel(
    const int* __restrict__ features, const float* __restrict__ thresholds,
    Pair* __restrict__ pairsA)
{
    int i = blockIdx.x * 256 + threadIdx.x;       // over 64*341
    if (i >= kTrees * 341) return;
    int t = i / 341;
    int e = i - t * 341;
    int p, m;
    if      (e < 1)  { p = 0; m = e; }
    else if (e < 5)  { p = 1; m = e - 1; }
    else if (e < 21) { p = 2; m = e - 5; }
    else if (e < 85) { p = 3; m = e - 21; }
    else             { p = 4; m = e - 85; }
    int g0 = (1 << (2 * p)) - 1 + m;              // global node id at level 2p
    int b  = t * kInternal;
    Pair pr;
    pr.thr0 = thresholds[b + g0];
    pr.thrL = thresholds[b + 2 * g0 + 1];
    pr.thrR = thresholds[b + 2 * g0 + 2];
    pr.meta = (unsigned)features[b + g0]
            | ((unsigned)features[b + 2 * g0 + 1] << 6)
            | ((unsigned)features[b + 2 * g0 + 2] << 12);
    pairsA[(t << 9) + e] = pr;
}

__global__ __launch_bounds__(256) void pack_sub_kernel(
    const int* __restrict__ features, const float* __restrict__ thresholds,
    const int* __restrict__ leaf_values, Sub16* __restrict__ subsA)
{
    int i = blockIdx.x * 256 + threadIdx.x;       // over 64*1024
    if (i >= kTrees * 1024) return;
    int t = i >> 10;
    int j = i & 1023;                              // level-10 local index
    int n10 = 1023 + j;
    int b   = t * kInternal;
    Sub16 sb;
    sb.thr10 = thresholds[b + n10];
    sb.thrL  = thresholds[b + 2 * n10 + 1];
    sb.thrR  = thresholds[b + 2 * n10 + 2];
    const int* lv = leaf_values + ((t << 12) + 4 * j);
    sb.meta = (unsigned)features[b + n10]
            | ((unsigned)features[b + 2 * n10 + 1] << 6)
            | ((unsigned)features[b + 2 * n10 + 2] << 12)
            | ((unsigned)lv[0] << 18) | ((unsigned)lv[1] << 21)
            | ((unsigned)lv[2] << 24) | ((unsigned)lv[3] << 27);
    subsA[(t << 10) + j] = sb;
}

__global__ __launch_bounds__(TPB, 4) void forest_kernel(
    const float* __restrict__ X,
    const Pair*  __restrict__ pairsA,   // [64][512] (341 used)
    const Sub16* __restrict__ subsA,    // [64][1024]
    int* __restrict__ out)
{
    extern __shared__ float xs[];                  // [64][512] feature-major
    const int tid  = threadIdx.x;
    const int s    = tid & (SPB - 1);              // sample slot 0..511
    const int h    = tid >> 9;                     // half-window 0..1
    const int base = blockIdx.x * SPB;

    // Stage: both threads of a sample each load half its row (8 float4).
    // LDS writes at f*512+s -> bank = s%32, consecutive lanes = 2-way (free).
    {
        const float4* Xr = (const float4*)(X + (size_t)(base + s) * kFeat) + h * 8;
        #pragma unroll
        for (int k = 0; k < 8; ++k) {
            float4 v = Xr[k];
            int f0 = (h * 8 + k) * 4;
            xs[(f0 + 0) * XSTR + s] = v.x;
            xs[(f0 + 1) * XSTR + s] = v.y;
            xs[(f0 + 2) * XSTR + s] = v.z;
            xs[(f0 + 3) * XSTR + s] = v.w;
        }
    }
    __syncthreads();

    const char* xb = (const char*)xs + (s << 2);   // + (f<<11) per access
    unsigned long long votes = 0ull;

    const int mofs[4] = {0, 1, 5, 21};             // shallow pair offsets

    for (int w = 0; w < kTrees / WINDOW; ++w) {
        const int t0 = w * WINDOW + h * ILP;       // my 4 trees of this window
        int m[ILP];
        #pragma unroll
        for (int j = 0; j < ILP; ++j) m[j] = 0;

        #pragma unroll
        for (int p = 0; p < 4; ++p) {              // levels 0..7 (L1-resident)
            #pragma unroll
            for (int j = 0; j < ILP; ++j) {        // 4 independent chains
                Pair pr = pairsA[((t0 + j) << 9) + mofs[p] + m[j]];
                float x0 = *(const float*)(xb + ((pr.meta & 63u) << 11));
                int c0 = x0 > pr.thr0 ? 1 : 0;
                float thr1     = c0 ? pr.thrR : pr.thrL;
                unsigned fsel  = c0 ? (pr.meta >> 12) : (pr.meta >> 6);
                float x1 = *(const float*)(xb + ((fsel & 63u) << 11));
                int c1 = x1 > thr1 ? 1 : 0;
                m[j] = 4 * m[j] + 2 * c0 + c1;
            }
        }

        #pragma unroll
        for (int j = 0; j < ILP; ++j) {            // levels 8,9 (pair4, L1 32KiB)
            Pair pr = pairsA[((t0 + j) << 9) + 85 + m[j]];
            float x0 = *(const float*)(xb + ((pr.meta & 63u) << 11));
            int c0 = x0 > pr.thr0 ? 1 : 0;
            float thr1     = c0 ? pr.thrR : pr.thrL;
            unsigned fsel  = c0 ? (pr.meta >> 12) : (pr.meta >> 6);
            float x1 = *(const float*)(xb + ((fsel & 63u) << 11));
            int c1 = x1 > thr1 ? 1 : 0;
            m[j] = 4 * m[j] + 2 * c0 + c1;
        }

        #pragma unroll
        for (int j = 0; j < ILP; ++j) {            // levels 10,11 + leaf: NT load
            const u32x4* sp = (const u32x4*)(subsA + ((t0 + j) << 10) + m[j]);
            u32x4 v = __builtin_nontemporal_load(sp);   // no L1 alloc
            float thr10 = __uint_as_float(v.x);
            float thrL  = __uint_as_float(v.y);
            float thrR  = __uint_as_float(v.z);
            unsigned mt = v.w;
            float x0 = *(const float*)(xb + ((mt & 63u) << 11));
            int c0 = x0 > thr10 ? 1 : 0;
            float thr1    = c0 ? thrR : thrL;
            unsigned fsel = c0 ? (mt >> 12) : (mt >> 6);
            float x1 = *(const float*)(xb + ((fsel & 63u) << 11));
            int c1 = x1 > thr1 ? 1 : 0;
            int cls = (mt >> (18 + 3 * ((c0 << 1) | c1))) & 7;
            votes += 1ull << (cls << 3);
        }

        __syncthreads();   // keep the whole CU on one 8-tree window
    }

    // Combine the two half-forest vote vectors through LDS (xs is dead now).
    unsigned long long* vbuf = (unsigned long long*)xs;
    if (h == 1) vbuf[s] = votes;
    __syncthreads();
    if (h == 0) {
        votes += vbuf[s];
        // argmax over 8 packed byte counters; strict '>' keeps smallest class
        int best = 0;
        int bc   = (int)(votes & 0xFFull);
        #pragma unroll
        for (int c = 1; c < kClasses; ++c) {
            int cnt = (int)((votes >> (c * 8)) & 0xFFull);
            if (cnt > bc) { bc = cnt; best = c; }
        }
        out[base + s] = best;
    }
}

extern "C" void kernel_launch(void* const* d_in, const int* in_sizes, int n_in,
                              void* d_out, int out_size, void* d_ws, size_t ws_size,
                              hipStream_t stream) {
    const float* X          = (const float*)d_in[0];
    const int*   features   = (const int*)d_in[1];
    const float* thresholds = (const float*)d_in[2];
    const int*   leaves     = (const int*)d_in[3];
    int*         out        = (int*)d_out;

    Pair*  pairsA = (Pair*)d_ws;                            // 64*512*16 = 512 KiB
    Sub16* subsA  = (Sub16*)((char*)d_ws + (kTrees << 13)); // +512 KiB, 1 MiB

    (void)hipFuncSetAttribute((const void*)forest_kernel,
                              hipFuncAttributeMaxDynamicSharedMemorySize,
                              XLDS_BYTES);

    pack_pairs_kernel<<<(kTrees * 341 + 255) / 256, 256, 0, stream>>>(
        features, thresholds, pairsA);
    pack_sub_kernel<<<(kTrees * 1024 + 255) / 256, 256, 0, stream>>>(
        features, thresholds, leaves, subsA);
    forest_kernel<<<kSamples / SPB, TPB, XLDS_BYTES, stream>>>(
        X, pairsA, subsA, out);
}